// Round 12
// baseline (195.000 us; speedup 1.0000x reference)
//
#include <hip/hip_runtime.h>
#include <math.h>

#define Bc 32
#define Sc 2048
#define Dc 1024
#define Mc 1024
#define LNEPS 1e-5f
#define SCv (1.f/67108864.f)   // 1/(B*S*M)

typedef float f32x4 __attribute__((ext_vector_type(4)));

__device__ __forceinline__ float4 f4add(float4 a, float4 b) {
    return make_float4(a.x + b.x, a.y + b.y, a.z + b.z, a.w + b.w);
}

__device__ __forceinline__ void dreduce(float& a, float& b, float* sm) {
#pragma unroll
    for (int o = 32; o; o >>= 1) { a += __shfl_xor(a, o); b += __shfl_xor(b, o); }
    int w = threadIdx.x >> 6;
    if ((threadIdx.x & 63) == 0) { sm[w] = a; sm[4 + w] = b; }
    __syncthreads();
    a = sm[0] + sm[1] + sm[2] + sm[3];
    b = sm[4] + sm[5] + sm[6] + sm[7];
    __syncthreads();
}

__device__ __forceinline__ void wreduce(float& a, float& b) {
#pragma unroll
    for (int o = 32; o; o >>= 1) { a += __shfl_xor(a, o); b += __shfl_xor(b, o); }
}

// XCD swizzles (dispatch assumed round-robin bid%8)
// KS16 NT kernels (1024 blocks): slice = (ks,n0i) in [0,256), shared by 4 b0i
__device__ __forceinline__ void nt_map16(int t, int& n0i, int& b0i, int& ks) {
    int xcd = t & 7, rest = t >> 3;      // [0,128)
    b0i = rest & 3;
    int q = rest >> 2;                   // [0,32)
    int s = q * 8 + xcd;                 // [0,256)
    ks = s >> 4; n0i = s & 15;
}
// T kernels (1024 blocks): slice = (dc,mc) in [0,32), shared by 32 b
__device__ __forceinline__ void t_map(int t, int& dc, int& b, int& mc) {
    int xcd = t & 7, rest = t >> 3;
    b = rest & 31;
    int q = rest >> 5;
    int s = q * 8 + xcd;
    dc = s >> 3; mc = s & 7;
}

// A-tile [8][64] from A[32][1024]
__device__ __forceinline__ void load_A64(float* Atile, const float* A, int b0, int k0) {
    for (int i = threadIdx.x; i < 512; i += 256) {
        int r = i >> 6, c = i & 63;
        Atile[i] = A[(size_t)(b0 + r) * 1024 + k0 + c];
    }
}

// NT inner (K-chunk 64): Atile[8][64] x W[k0..+64)[n0..+64) -> P[ks][b][n], ks<16
__device__ __forceinline__ void nt_inner64v(const float* Atile, const float* W, int k0, int n0,
                                            float* P, int ks, int b0) {
    int lane = threadIdx.x & 63, bl = threadIdx.x >> 6;
    int n4 = lane & 15, kg = lane >> 4;
    const float* a0 = Atile + bl * 64;
    const float* a1 = Atile + (bl + 4) * 64;
    const float4* Wp = (const float4*)(W + (size_t)k0 * 1024 + n0);
    float4 acc0 = make_float4(0.f, 0.f, 0.f, 0.f);
    float4 acc1 = make_float4(0.f, 0.f, 0.f, 0.f);
#pragma unroll 8
    for (int i = 0; i < 16; ++i) {
        int k = i * 4 + kg;
        float4 w4 = Wp[(size_t)k * 256 + n4];
        float av0 = a0[k], av1 = a1[k];
        acc0.x = fmaf(av0, w4.x, acc0.x); acc0.y = fmaf(av0, w4.y, acc0.y);
        acc0.z = fmaf(av0, w4.z, acc0.z); acc0.w = fmaf(av0, w4.w, acc0.w);
        acc1.x = fmaf(av1, w4.x, acc1.x); acc1.y = fmaf(av1, w4.y, acc1.y);
        acc1.z = fmaf(av1, w4.z, acc1.z); acc1.w = fmaf(av1, w4.w, acc1.w);
    }
#pragma unroll
    for (int o = 16; o <= 32; o <<= 1) {
        acc0.x += __shfl_xor(acc0.x, o); acc0.y += __shfl_xor(acc0.y, o);
        acc0.z += __shfl_xor(acc0.z, o); acc0.w += __shfl_xor(acc0.w, o);
        acc1.x += __shfl_xor(acc1.x, o); acc1.y += __shfl_xor(acc1.y, o);
        acc1.z += __shfl_xor(acc1.z, o); acc1.w += __shfl_xor(acc1.w, o);
    }
    if (kg == 0) {
        size_t base = (size_t)ks * 32768 + n0 + 4 * n4;
        *(float4*)&P[base + (size_t)(b0 + bl) * 1024] = acc0;
        *(float4*)&P[base + (size_t)(b0 + bl + 4) * 1024] = acc1;
    }
}

__device__ __forceinline__ void t_inner(const float* Asl, const float* W,
                                        int dbase, int m0, float* outp) {
    int lane = threadIdx.x & 63, wv = threadIdx.x >> 6;
    int half = lane >> 5, m4 = lane & 31;
    float4 a4 = ((const float4*)Asl)[m4];
    int d0 = dbase + wv * 64 + half;
    float res = 0.f;
#pragma unroll 8
    for (int p = 0; p < 32; ++p) {
        int d = d0 + p * 2;
        float4 w4 = ((const float4*)(W + (size_t)d * 1024 + m0))[m4];
        float v = w4.x * a4.x + w4.y * a4.y + w4.z * a4.z + w4.w * a4.w;
#pragma unroll
        for (int o = 1; o < 32; o <<= 1) v += __shfl_xor(v, o);
        res = (m4 == p) ? v : res;
    }
    outp[wv * 64 + m4 * 2 + half] = res;
}

// K1: wv_row/bvsum (bid<256) + mem@W0 partials (1024, KS16). grid 1280
__global__ __launch_bounds__(256) void k_front(const float* __restrict__ Wv, const float* __restrict__ bv,
                        const float* __restrict__ mem, const float* __restrict__ W0,
                        float* __restrict__ wv_row, float* __restrict__ bvsum,
                        float* __restrict__ P1a) {
    __shared__ float shm[520];
    int bid = blockIdx.x, tid = threadIdx.x;
    if (bid < 256) {
        float s1 = 0.f, s2 = 0.f, s3 = 0.f, s4 = 0.f;
        for (int m = tid; m < 1024; m += 256) {
            s1 += Wv[(size_t)bid * 1024 + m];
            s2 += Wv[(size_t)(bid + 256) * 1024 + m];
            s3 += Wv[(size_t)(bid + 512) * 1024 + m];
            s4 += Wv[(size_t)(bid + 768) * 1024 + m];
        }
        dreduce(s1, s2, shm + 512);
        dreduce(s3, s4, shm + 512);
        if (tid == 0) {
            wv_row[bid] = s1; wv_row[bid + 256] = s2;
            wv_row[bid + 512] = s3; wv_row[bid + 768] = s4;
        }
        if (bid == 0) {
            float v = 0.f, d2 = 0.f;
            for (int m = tid; m < 1024; m += 256) v += bv[m];
            dreduce(v, d2, shm + 512);
            if (tid == 0) *bvsum = v;
        }
    } else {
        int n0i, b0i, ks;
        nt_map16(bid - 256, n0i, b0i, ks);
        int n0 = n0i * 64, b0 = b0i * 8, k0 = ks * 64;
        load_A64(shm, mem, b0, k0);
        __syncthreads();
        nt_inner64v(shm, W0, k0, n0, P1a, ks, b0);
    }
}

// K2/K10: h = SiLU(LN(bias + sum16 P)) tile, then @W1 -> Pout. grid 1024 (KS16)
__global__ __launch_bounds__(256) void k_gemm_ln(const float* __restrict__ P, const float* __restrict__ bias,
                          const float* __restrict__ g, const float* __restrict__ be,
                          const float* __restrict__ W1, float* __restrict__ Pout) {
    __shared__ float shm[536];
    int tid = threadIdx.x;
    int n0i, b0i, ks;
    nt_map16(blockIdx.x, n0i, b0i, ks);
    int n0 = n0i * 64, b0 = b0i * 8, k0 = ks * 64;
    float* Atile = shm; float* stats = shm + 512;
    int wv = tid >> 6, lane = tid & 63;
    const float4* b4 = (const float4*)bias;
    for (int rr = 0; rr < 2; ++rr) {
        int r = wv + rr * 4, b = b0 + r;
        float s = 0.f, sq = 0.f;
#pragma unroll
        for (int q = 0; q < 4; ++q) {
            int m4 = lane + 64 * q;
            float4 z4 = b4[m4];
#pragma unroll
            for (int k2 = 0; k2 < 16; ++k2) {
                float4 v = ((const float4*)(P + (size_t)k2 * 32768 + (size_t)b * 1024))[m4];
                z4 = f4add(z4, v);
            }
            int c0 = 4 * m4 - k0;
            if ((unsigned)c0 < 64u) *(float4*)(Atile + r * 64 + c0) = z4;
            s += z4.x + z4.y + z4.z + z4.w;
            sq += z4.x * z4.x + z4.y * z4.y + z4.z * z4.z + z4.w * z4.w;
        }
        wreduce(s, sq);
        if (lane == 0) {
            float mean = s * (1.f / 1024.f);
            stats[r] = mean;
            stats[8 + r] = rsqrtf(sq * (1.f / 1024.f) - mean * mean + LNEPS);
        }
    }
    __syncthreads();
    for (int i = tid; i < 512; i += 256) {
        int r = i >> 6, c = i & 63, m = k0 + c;
        float xh = (Atile[i] - stats[r]) * stats[8 + r];
        float y = fmaf(xh, g[m], be[m]);
        float sg = 1.f / (1.f + __expf(-y));
        Atile[i] = y * sg;
    }
    __syncthreads();
    nt_inner64v(Atile, W1, k0, n0, Pout, ks, b0);
}

// K3: LN2 recompute + cb partial + mo@Wk^T slice. grid 1024 (swizzled T)
__global__ __launch_bounds__(256) void k_wpart(const float* __restrict__ P2a, const float* __restrict__ memb1,
                        const float* __restrict__ lng1, const float* __restrict__ lnb1,
                        const float* __restrict__ bk, const float* __restrict__ Wk,
                        float* __restrict__ wpart, float* __restrict__ cbpart) {
    __shared__ float shm[136];
    int tid = threadIdx.x;
    int dc, b, mc;
    t_map(blockIdx.x, dc, b, mc);
    int m0 = mc * 128;
    float* red = shm + 128;
    float4 z4 = ((const float4*)memb1)[tid];
#pragma unroll
    for (int k2 = 0; k2 < 16; ++k2) {
        float4 v = ((const float4*)(P2a + (size_t)k2 * 32768 + (size_t)b * 1024))[tid];
        z4 = f4add(z4, v);
    }
    float s = z4.x + z4.y + z4.z + z4.w;
    float sq = z4.x * z4.x + z4.y * z4.y + z4.z * z4.z + z4.w * z4.w;
    int c0 = 4 * tid - m0;
    if ((unsigned)c0 < 128u) *(float4*)(shm + c0) = z4;
    dreduce(s, sq, red);
    float mean = s * (1.f / 1024.f);
    float rstd = rsqrtf(sq * (1.f / 1024.f) - mean * mean + LNEPS);
    if (tid < 128) {
        int m = m0 + tid;
        float xh = (shm[tid] - mean) * rstd;
        float y = fmaf(xh, lng1[m], lnb1[m]);
        float sg = 1.f / (1.f + __expf(-y));
        shm[tid] = y * sg;
    }
    __syncthreads();
    if (dc == 0) {
        float c = (tid < 128) ? bk[m0 + tid] * shm[tid] : 0.f;
        float d2 = 0.f;
        dreduce(c, d2, red);
        if (tid == 0) cbpart[mc * 32 + b] = c;
    }
    t_inner(shm, Wk, dc * 256, m0, wpart + (size_t)(mc * 32 + b) * 1024 + dc * 256);
}

// K4: one pass over X (NT loads) + 2048 rider blocks (KS16 mem@{Wf_bot,Wu_bot}).
// grid 3072, 1D. No cross-block sync anywhere.
__global__ __launch_bounds__(256) void k_bigpass(const float* __restrict__ X, const float* __restrict__ wpart,
                          const float* __restrict__ wv_row, const float* __restrict__ cbpart,
                          const float* __restrict__ bvsum, const float* __restrict__ mem,
                          const float* __restrict__ Wfb, const float* __restrict__ Wub,
                          float* __restrict__ t_part, float* __restrict__ p_part,
                          float* __restrict__ rs_part,
                          float* __restrict__ Pfm, float* __restrict__ Pum) {
    __shared__ float red[4][1024];
    __shared__ float rsum_s[4];
    int bid = blockIdx.x;
    if (bid >= 1024) {   // riders: X-independent gate GEMMs
        int t = bid - 1024, z = t >> 10;
        int n0i, b0i, ks;
        nt_map16(t & 1023, n0i, b0i, ks);
        int n0 = n0i * 64, b0 = b0i * 8, k0 = ks * 64;
        float* Atile = &red[0][0];
        load_A64(Atile, mem, b0, k0);
        __syncthreads();
        if (z == 0) nt_inner64v(Atile, Wfb, k0, n0, Pfm, ks, b0);
        else        nt_inner64v(Atile, Wub, k0, n0, Pum, ks, b0);
        return;
    }
    int b = bid >> 5, ch = bid & 31;
    int wv = threadIdx.x >> 6, lane = threadIdx.x & 63;
    float4 wreg[4], tacc[4], pacc[4];
    const float4* wp4 = (const float4*)wpart;
    const float4* wr4 = (const float4*)wv_row;
#pragma unroll
    for (int j = 0; j < 4; ++j) {
        int d4 = lane + 64 * j;
        float4 a = make_float4(0.f, 0.f, 0.f, 0.f);
#pragma unroll
        for (int mc = 0; mc < 8; ++mc) a = f4add(a, wp4[(size_t)(mc * 32 + b) * 256 + d4]);
        float4 wr = wr4[d4];
        wreg[j].x = 1024.f * a.x - wr.x;
        wreg[j].y = 1024.f * a.y - wr.y;
        wreg[j].z = 1024.f * a.z - wr.z;
        wreg[j].w = 1024.f * a.w - wr.w;
        tacc[j] = make_float4(0.f, 0.f, 0.f, 0.f);
        pacc[j] = make_float4(0.f, 0.f, 0.f, 0.f);
    }
    float cbs = 0.f;
#pragma unroll
    for (int mc = 0; mc < 8; ++mc) cbs += cbpart[mc * 32 + b];
    float cbv = 1024.f * cbs - *bvsum;
    float rloc = 0.f;
    int s0r = ch * 64 + wv * 16;
#pragma unroll 2
    for (int i = 0; i < 16; ++i) {
        const f32x4* xr = (const f32x4*)(X + ((size_t)b * Sc + s0r + i) * Dc);
        f32x4 x[4]; float pp = 0.f;
#pragma unroll
        for (int j = 0; j < 4; ++j) {
            x[j] = __builtin_nontemporal_load(xr + lane + 64 * j);
            pp += x[j].x * wreg[j].x + x[j].y * wreg[j].y + x[j].z * wreg[j].z + x[j].w * wreg[j].w;
        }
#pragma unroll
        for (int o = 32; o; o >>= 1) pp += __shfl_xor(pp, o);
        float r = pp + cbv;
        rloc += r;
#pragma unroll
        for (int j = 0; j < 4; ++j) {
            tacc[j].x = fmaf(x[j].x, r, tacc[j].x);
            tacc[j].y = fmaf(x[j].y, r, tacc[j].y);
            tacc[j].z = fmaf(x[j].z, r, tacc[j].z);
            tacc[j].w = fmaf(x[j].w, r, tacc[j].w);
            pacc[j].x += x[j].x; pacc[j].y += x[j].y;
            pacc[j].z += x[j].z; pacc[j].w += x[j].w;
        }
    }
    float4* redv = (float4*)red[wv];
#pragma unroll
    for (int j = 0; j < 4; ++j) redv[lane + 64 * j] = tacc[j];
    if (lane == 0) rsum_s[wv] = rloc;
    __syncthreads();
    size_t pb = ((size_t)b * 32 + ch) * 1024;
    for (int j = 0; j < 4; ++j) {
        int d = threadIdx.x + 256 * j;
        t_part[pb + d] = red[0][d] + red[1][d] + red[2][d] + red[3][d];
    }
    if (threadIdx.x == 0) rs_part[b * 32 + ch] = rsum_s[0] + rsum_s[1] + rsum_s[2] + rsum_s[3];
    __syncthreads();
#pragma unroll
    for (int j = 0; j < 4; ++j) redv[lane + 64 * j] = pacc[j];
    __syncthreads();
    for (int j = 0; j < 4; ++j) {
        int d = threadIdx.x + 256 * j;
        p_part[pb + d] = red[0][d] + red[1][d] + red[2][d] + red[3][d];
    }
}

// K5: chunk reduce -> tbuf, pooled(scaled), rsv. grid 32
__global__ __launch_bounds__(256) void k_reduce(const float* __restrict__ t_part, const float* __restrict__ p_part,
                         const float* __restrict__ rs_part,
                         float* __restrict__ tbuf, float* __restrict__ pooled,
                         float* __restrict__ rsv) {
    int idx = blockIdx.x * 256 + threadIdx.x;      // [0, 8192) float4 slots
    int b = idx >> 8, d4 = idx & 255;
    const float4* tp = (const float4*)t_part + (size_t)b * 8192 + d4;
    const float4* pp = (const float4*)p_part + (size_t)b * 8192 + d4;
    float4 st = make_float4(0.f, 0.f, 0.f, 0.f);
    float4 sp = make_float4(0.f, 0.f, 0.f, 0.f);
#pragma unroll 8
    for (int ch = 0; ch < 32; ++ch) {
        st = f4add(st, tp[(size_t)ch * 256]);
        sp = f4add(sp, pp[(size_t)ch * 256]);
    }
    ((float4*)tbuf)[idx] = st;
    sp.x *= (1.f / 2048.f); sp.y *= (1.f / 2048.f);
    sp.z *= (1.f / 2048.f); sp.w *= (1.f / 2048.f);
    ((float4*)pooled)[idx] = sp;
    if (blockIdx.x == 0 && threadIdx.x < 32) {
        float s = 0.f;
        for (int ch = 0; ch < 32; ++ch) s += rs_part[threadIdx.x * 32 + ch];
        rsv[threadIdx.x] = s;
    }
}

// K6: 3 GEMMs in one launch (KS16). grid 3072
__global__ __launch_bounds__(256) void k_gates(const float* __restrict__ tbuf, const float* __restrict__ pooled,
                        const float* __restrict__ Wk, const float* __restrict__ Wf,
                        const float* __restrict__ Wu,
                        float* __restrict__ Pg, float* __restrict__ Pfp, float* __restrict__ Pup) {
    __shared__ float Atile[512];
    int bid = blockIdx.x;
    int z = bid >> 10;
    int n0i, b0i, ks;
    nt_map16(bid & 1023, n0i, b0i, ks);
    int n0 = n0i * 64, b0 = b0i * 8, k0 = ks * 64;
    const float* A; const float* W; float* P;
    if (z == 0)      { A = tbuf;   W = Wk; P = Pg; }
    else if (z == 1) { A = pooled; W = Wf; P = Pfp; }
    else             { A = pooled; W = Wu; P = Pup; }
    load_A64(Atile, A, b0, k0);
    __syncthreads();
    nt_inner64v(Atile, W, k0, n0, P, ks, b0);
}

// K7/K8: LN-bwd recompute + gemm-T slice. grid 1024 (swizzled T; rsv direct)
template <int NZ, int NG>
__global__ __launch_bounds__(256) void k_lnbwd_gemmT(const float* __restrict__ Pz, const float* __restrict__ bias,
                              const float* __restrict__ g, const float* __restrict__ be,
                              const float* __restrict__ Pgrad, int mode,
                              const float* __restrict__ bk, const float* __restrict__ rsv,
                              const float* __restrict__ W, float* __restrict__ Pout) {
    __shared__ float shm[392];
    int tid = threadIdx.x;
    int dc, b, mc;
    t_map(blockIdx.x, dc, b, mc);
    int m0 = mc * 128;
    float* red = shm + 384;
    float rsb = mode ? rsv[b] : 0.f;
    float4 z4 = ((const float4*)bias)[tid];
#pragma unroll
    for (int k2 = 0; k2 < NZ; ++k2) {
        float4 v = ((const float4*)(Pz + (size_t)k2 * 32768 + (size_t)b * 1024))[tid];
        z4 = f4add(z4, v);
    }
    float s = z4.x + z4.y + z4.z + z4.w;
    float sq = z4.x * z4.x + z4.y * z4.y + z4.z * z4.z + z4.w * z4.w;
    dreduce(s, sq, red);
    float mean = s * (1.f / 1024.f);
    float rstd = rsqrtf(sq * (1.f / 1024.f) - mean * mean + LNEPS);
    float4 g4 = make_float4(0.f, 0.f, 0.f, 0.f);
#pragma unroll
    for (int k2 = 0; k2 < NG; ++k2) {
        float4 v = ((const float4*)(Pgrad + (size_t)k2 * 32768 + (size_t)b * 1024))[tid];
        g4 = f4add(g4, v);
    }
    if (mode) {
        float4 bk4 = ((const float4*)bk)[tid];
        g4.x = SCv * (g4.x + bk4.x * rsb);
        g4.y = SCv * (g4.y + bk4.y * rsb);
        g4.z = SCv * (g4.z + bk4.z * rsb);
        g4.w = SCv * (g4.w + bk4.w * rsb);
    }
    float4 gg = ((const float4*)g)[tid], bb = ((const float4*)be)[tid];
    float sa = 0.f, sax = 0.f;
    float4 a4, xh4;
    {
        xh4.x = (z4.x - mean) * rstd;
        float y = fmaf(xh4.x, gg.x, bb.x);
        float sg2 = 1.f / (1.f + __expf(-y));
        a4.x = g4.x * (sg2 * (1.f + y * (1.f - sg2))) * gg.x;
        sa += a4.x; sax += a4.x * xh4.x;
        xh4.y = (z4.y - mean) * rstd;
        y = fmaf(xh4.y, gg.y, bb.y);
        sg2 = 1.f / (1.f + __expf(-y));
        a4.y = g4.y * (sg2 * (1.f + y * (1.f - sg2))) * gg.y;
        sa += a4.y; sax += a4.y * xh4.y;
        xh4.z = (z4.z - mean) * rstd;
        y = fmaf(xh4.z, gg.z, bb.z);
        sg2 = 1.f / (1.f + __expf(-y));
        a4.z = g4.z * (sg2 * (1.f + y * (1.f - sg2))) * gg.z;
        sa += a4.z; sax += a4.z * xh4.z;
        xh4.w = (z4.w - mean) * rstd;
        y = fmaf(xh4.w, gg.w, bb.w);
        sg2 = 1.f / (1.f + __expf(-y));
        a4.w = g4.w * (sg2 * (1.f + y * (1.f - sg2))) * gg.w;
        sa += a4.w; sax += a4.w * xh4.w;
    }
    int c0 = 4 * tid - m0;
    if ((unsigned)c0 < 128u) {
        *(float4*)(shm + c0) = a4;
        *(float4*)(shm + 128 + c0) = xh4;
    }
    dreduce(sa, sax, red);
    float ma = sa * (1.f / 1024.f), mx = sax * (1.f / 1024.f);
    if (tid < 128) shm[256 + tid] = rstd * (shm[tid] - ma - shm[128 + tid] * mx);
    __syncthreads();
    t_inner(shm + 256, W, dc * 256, m0, Pout + (size_t)(mc * 32 + b) * 1024 + dc * 256);
}

// K9: gate/update recompute -> nmem tile -> @W0 partials (KS16); writes out_nm. grid 1024
__global__ __launch_bounds__(256) void k_upd_g3(const float* __restrict__ Pfm, const float* __restrict__ Pfp,
                         const float* __restrict__ Pum, const float* __restrict__ Pup,
                         const float* __restrict__ surp,
                         const float* __restrict__ bf, const float* __restrict__ bu,
                         const float* __restrict__ mem, const float* __restrict__ mom,
                         const float* __restrict__ eta, const float* __restrict__ theta,
                         const float* __restrict__ W0, float* __restrict__ P3a,
                         float* __restrict__ out_nm) {
    __shared__ float Atile[512];
    int tid = threadIdx.x;
    int n0i, b0i, ks;
    nt_map16(blockIdx.x, n0i, b0i, ks);
    int n0 = n0i * 64, b0 = b0i * 8, k0 = ks * 64;
    float etav = eta[0], thv = theta[0];
    if (tid < 128) {
        int r = tid >> 4, c4 = tid & 15, b = b0 + r;
        int m4 = (k0 >> 2) + c4;
        float4 zf = ((const float4*)bf)[m4];
        float4 zu = ((const float4*)bu)[m4];
        float4 sv = make_float4(0.f, 0.f, 0.f, 0.f);
#pragma unroll
        for (int k2 = 0; k2 < 16; ++k2) {
            size_t ob4 = (size_t)k2 * 8192 + (size_t)b * 256 + m4;
            zf = f4add(zf, f4add(((const float4*)Pfm)[ob4], ((const float4*)Pfp)[ob4]));
            zu = f4add(zu, f4add(((const float4*)Pum)[ob4], ((const float4*)Pup)[ob4]));
        }
#pragma unroll
        for (int k2 = 0; k2 < 8; ++k2) {
            size_t ob4 = (size_t)k2 * 8192 + (size_t)b * 256 + m4;
            sv = f4add(sv, ((const float4*)surp)[ob4]);
        }
        float4 me = ((const float4*)mem)[(size_t)b * 256 + m4];
        float4 mo = ((const float4*)mom)[(size_t)b * 256 + m4];
        float4 nm;
        {
            float f = 1.f / (1.f + __expf(-zf.x)), u = 1.f / (1.f + __expf(-zu.x));
            nm.x = (1.f - f) * me.x + u * (etav * mo.x + thv * sv.x);
            f = 1.f / (1.f + __expf(-zf.y)); u = 1.f / (1.f + __expf(-zu.y));
            nm.y = (1.f - f) * me.y + u * (etav * mo.y + thv * sv.y);
            f = 1.f / (1.f + __expf(-zf.z)); u = 1.f / (1.f + __expf(-zu.z));
            nm.z = (1.f - f) * me.z + u * (etav * mo.z + thv * sv.z);
            f = 1.f / (1.f + __expf(-zf.w)); u = 1.f / (1.f + __expf(-zu.w));
            nm.w = (1.f - f) * me.w + u * (etav * mo.w + thv * sv.w);
        }
        *(float4*)(Atile + r * 64 + 4 * c4) = nm;
        if (n0i == 0) ((float4*)out_nm)[(size_t)b * 256 + m4] = nm;
    }
    __syncthreads();
    nt_inner64v(Atile, W0, k0, n0, P3a, ks, b0);
}

// K11: final LN -> out. grid 32
__global__ __launch_bounds__(256) void k_final(const float* __restrict__ P4a, const float* __restrict__ memb1,
                        const float* __restrict__ lng1, const float* __restrict__ lnb1,
                        float* __restrict__ out) {
    __shared__ float sm[8];
    int b = blockIdx.x, tid = threadIdx.x;
    float4 z4 = ((const float4*)memb1)[tid];
#pragma unroll
    for (int k2 = 0; k2 < 16; ++k2) {
        float4 v = ((const float4*)(P4a + (size_t)k2 * 32768 + (size_t)b * 1024))[tid];
        z4 = f4add(z4, v);
    }
    float s = z4.x + z4.y + z4.z + z4.w;
    float sq = z4.x * z4.x + z4.y * z4.y + z4.z * z4.z + z4.w * z4.w;
    dreduce(s, sq, sm);
    float mean = s * (1.f / 1024.f);
    float rstd = rsqrtf(sq * (1.f / 1024.f) - mean * mean + LNEPS);
    float4 gg = ((const float4*)lng1)[tid], bb = ((const float4*)lnb1)[tid];
    float4 o;
    {
        float xh = (z4.x - mean) * rstd, y = fmaf(xh, gg.x, bb.x);
        o.x = y / (1.f + __expf(-y));
        xh = (z4.y - mean) * rstd; y = fmaf(xh, gg.y, bb.y);
        o.y = y / (1.f + __expf(-y));
        xh = (z4.z - mean) * rstd; y = fmaf(xh, gg.z, bb.z);
        o.z = y / (1.f + __expf(-y));
        xh = (z4.w - mean) * rstd; y = fmaf(xh, gg.w, bb.w);
        o.w = y / (1.f + __expf(-y));
    }
    ((float4*)out)[(size_t)b * 256 + tid] = o;
}

extern "C" void kernel_launch(void* const* d_in, const int* in_sizes, int n_in,
                              void* d_out, int out_size, void* d_ws, size_t ws_size,
                              hipStream_t stream) {
    const float* X    = (const float*)d_in[0];
    const float* mem  = (const float*)d_in[1];
    const float* mom  = (const float*)d_in[2];
    const float* Wk   = (const float*)d_in[3];
    const float* bk   = (const float*)d_in[4];
    const float* Wv   = (const float*)d_in[5];
    const float* bv   = (const float*)d_in[6];
    const float* memW = (const float*)d_in[7];
    const float* memb = (const float*)d_in[8];
    const float* lng  = (const float*)d_in[9];
    const float* lnb  = (const float*)d_in[10];
    const float* Wf   = (const float*)d_in[11];
    const float* bf   = (const float*)d_in[12];
    const float* Wu   = (const float*)d_in[15];
    const float* bu   = (const float*)d_in[16];
    const float* eta  = (const float*)d_in[17];
    const float* theta= (const float*)d_in[18];
    float* out = (float*)d_out;

    const size_t BM = (size_t)Bc * Mc;     // 32768
    float* ws = (float*)d_ws;
    float* P1a    = ws;                    // 16*BM each (KS16)
    float* P2a    = ws + 16 * BM;
    float* Pg     = ws + 32 * BM;
    float* Pfp    = ws + 48 * BM;
    float* Pup    = ws + 64 * BM;
    float* Pfm    = ws + 80 * BM;
    float* Pum    = ws + 96 * BM;
    float* P3a    = ws + 112 * BM;
    float* P4a    = ws + 128 * BM;
    float* wpart  = ws + 144 * BM;         // 8*BM
    float* ghp    = ws + 152 * BM;         // 8*BM
    float* surp   = ws + 160 * BM;         // 8*BM
    float* t_part = ws + 168 * BM;         // 32*BM
    float* p_part = ws + 200 * BM;         // 32*BM
    float* tbuf   = ws + 232 * BM;         // BM
    float* pooled = ws + 233 * BM;         // BM
    float* wv_row = ws + 234 * BM;         // 1024
    float* bvsum  = wv_row + 1024;         // 1
    float* cbpart = bvsum + 1;             // 256
    float* rs_part= cbpart + 256;          // 1024
    float* rsv    = rs_part + 1024;        // 32

    const float* W0 = memW;
    const float* W1 = memW + (size_t)Mc * Mc;
    const float* Wfb = Wf + (size_t)1024 * 1024;
    const float* Wub = Wu + (size_t)1024 * 1024;

    k_front<<<1280, 256, 0, stream>>>(Wv, bv, mem, W0, wv_row, bvsum, P1a);
    k_gemm_ln<<<1024, 256, 0, stream>>>(P1a, memb, lng, lnb, W1, P2a);
    k_wpart<<<1024, 256, 0, stream>>>(P2a, memb + 1024, lng + 1024, lnb + 1024, bk, Wk, wpart, cbpart);
    k_bigpass<<<3072, 256, 0, stream>>>(X, wpart, wv_row, cbpart, bvsum, mem, Wfb, Wub,
                                        t_part, p_part, rs_part, Pfm, Pum);
    k_reduce<<<32, 256, 0, stream>>>(t_part, p_part, rs_part, tbuf, pooled, rsv);
    k_gates<<<3072, 256, 0, stream>>>(tbuf, pooled, Wk, Wf, Wu, Pg, Pfp, Pup);
    k_lnbwd_gemmT<16, 16><<<1024, 256, 0, stream>>>(P2a, memb + 1024, lng + 1024, lnb + 1024, Pg, 1, bk, rsv, W1, ghp);
    k_lnbwd_gemmT<16, 8><<<1024, 256, 0, stream>>>(P1a, memb, lng, lnb, ghp, 0, bk, rsv, W0, surp);
    k_upd_g3<<<1024, 256, 0, stream>>>(Pfm, Pfp, Pum, Pup, surp, bf, bu, mem, mom, eta, theta, W0, P3a, out + BM);
    k_gemm_ln<<<1024, 256, 0, stream>>>(P3a, memb, lng, lnb, W1, P4a);
    k_final<<<32, 256, 0, stream>>>(P4a, memb + 1024, lng + 1024, lnb + 1024, out);
}

// Round 13
// 155.917 us; speedup vs baseline: 1.2507x; 1.2507x over previous
//
#include <hip/hip_runtime.h>
#include <math.h>

#define Bc 32
#define Sc 2048
#define Dc 1024
#define Mc 1024
#define LNEPS 1e-5f
#define SCv (1.f/67108864.f)   // 1/(B*S*M)

typedef float f32x4 __attribute__((ext_vector_type(4)));

__device__ __forceinline__ float4 f4add(float4 a, float4 b) {
    return make_float4(a.x + b.x, a.y + b.y, a.z + b.z, a.w + b.w);
}

__device__ __forceinline__ void dreduce(float& a, float& b, float* sm) {
#pragma unroll
    for (int o = 32; o; o >>= 1) { a += __shfl_xor(a, o); b += __shfl_xor(b, o); }
    int w = threadIdx.x >> 6;
    if ((threadIdx.x & 63) == 0) { sm[w] = a; sm[4 + w] = b; }
    __syncthreads();
    a = sm[0] + sm[1] + sm[2] + sm[3];
    b = sm[4] + sm[5] + sm[6] + sm[7];
    __syncthreads();
}

__device__ __forceinline__ void wreduce(float& a, float& b) {
#pragma unroll
    for (int o = 32; o; o >>= 1) { a += __shfl_xor(a, o); b += __shfl_xor(b, o); }
}

// XCD swizzles (dispatch assumed round-robin bid%8)
__device__ __forceinline__ void nt_map(int t, int& n0i, int& b0i, int& ks) {
    int xcd = t & 7, rest = t >> 3;
    b0i = rest & 3;
    int q = rest >> 2;
    int s = q * 8 + xcd;
    ks = s >> 4; n0i = s & 15;
}
__device__ __forceinline__ void t_map(int t, int& dc, int& b, int& mc) {
    int xcd = t & 7, rest = t >> 3;
    b = rest & 31;
    int q = rest >> 5;
    int s = q * 8 + xcd;
    dc = s >> 3; mc = s & 7;
}

__device__ __forceinline__ void load_A128(float* Atile, const float* A, int b0, int k0) {
    for (int i = threadIdx.x; i < 1024; i += 256) {
        int r = i >> 7, c = i & 127;
        Atile[i] = A[(size_t)(b0 + r) * 1024 + k0 + c];
    }
}

__device__ __forceinline__ void nt_inner128v(const float* Atile, const float* W, int k0, int n0,
                                             float* P, int ks, int b0) {
    int lane = threadIdx.x & 63, bl = threadIdx.x >> 6;
    int n4 = lane & 15, kg = lane >> 4;
    const float* a0 = Atile + bl * 128;
    const float* a1 = Atile + (bl + 4) * 128;
    const float4* Wp = (const float4*)(W + (size_t)k0 * 1024 + n0);
    float4 acc0 = make_float4(0.f, 0.f, 0.f, 0.f);
    float4 acc1 = make_float4(0.f, 0.f, 0.f, 0.f);
#pragma unroll 8
    for (int i = 0; i < 32; ++i) {
        int k = i * 4 + kg;
        float4 w4 = Wp[(size_t)k * 256 + n4];
        float av0 = a0[k], av1 = a1[k];
        acc0.x = fmaf(av0, w4.x, acc0.x); acc0.y = fmaf(av0, w4.y, acc0.y);
        acc0.z = fmaf(av0, w4.z, acc0.z); acc0.w = fmaf(av0, w4.w, acc0.w);
        acc1.x = fmaf(av1, w4.x, acc1.x); acc1.y = fmaf(av1, w4.y, acc1.y);
        acc1.z = fmaf(av1, w4.z, acc1.z); acc1.w = fmaf(av1, w4.w, acc1.w);
    }
#pragma unroll
    for (int o = 16; o <= 32; o <<= 1) {
        acc0.x += __shfl_xor(acc0.x, o); acc0.y += __shfl_xor(acc0.y, o);
        acc0.z += __shfl_xor(acc0.z, o); acc0.w += __shfl_xor(acc0.w, o);
        acc1.x += __shfl_xor(acc1.x, o); acc1.y += __shfl_xor(acc1.y, o);
        acc1.z += __shfl_xor(acc1.z, o); acc1.w += __shfl_xor(acc1.w, o);
    }
    if (kg == 0) {
        size_t base = (size_t)ks * 32768 + n0 + 4 * n4;
        *(float4*)&P[base + (size_t)(b0 + bl) * 1024] = acc0;
        *(float4*)&P[base + (size_t)(b0 + bl + 4) * 1024] = acc1;
    }
}

__device__ __forceinline__ void t_inner(const float* Asl, const float* W,
                                        int dbase, int m0, float* outp) {
    int lane = threadIdx.x & 63, wv = threadIdx.x >> 6;
    int half = lane >> 5, m4 = lane & 31;
    float4 a4 = ((const float4*)Asl)[m4];
    int d0 = dbase + wv * 64 + half;
    float res = 0.f;
#pragma unroll 8
    for (int p = 0; p < 32; ++p) {
        int d = d0 + p * 2;
        float4 w4 = ((const float4*)(W + (size_t)d * 1024 + m0))[m4];
        float v = w4.x * a4.x + w4.y * a4.y + w4.z * a4.z + w4.w * a4.w;
#pragma unroll
        for (int o = 1; o < 32; o <<= 1) v += __shfl_xor(v, o);
        res = (m4 == p) ? v : res;
    }
    outp[wv * 64 + m4 * 2 + half] = res;
}

// K1: wv_row/bvsum (bid<256) + mem@W0 partials (512, swizzled). grid 768
__global__ __launch_bounds__(256) void k_front(const float* __restrict__ Wv, const float* __restrict__ bv,
                        const float* __restrict__ mem, const float* __restrict__ W0,
                        float* __restrict__ wv_row, float* __restrict__ bvsum,
                        float* __restrict__ P1a) {
    __shared__ float shm[1032];
    int bid = blockIdx.x, tid = threadIdx.x;
    if (bid < 256) {
        float s1 = 0.f, s2 = 0.f, s3 = 0.f, s4 = 0.f;
        for (int m = tid; m < 1024; m += 256) {
            s1 += Wv[(size_t)bid * 1024 + m];
            s2 += Wv[(size_t)(bid + 256) * 1024 + m];
            s3 += Wv[(size_t)(bid + 512) * 1024 + m];
            s4 += Wv[(size_t)(bid + 768) * 1024 + m];
        }
        dreduce(s1, s2, shm + 1024);
        dreduce(s3, s4, shm + 1024);
        if (tid == 0) {
            wv_row[bid] = s1; wv_row[bid + 256] = s2;
            wv_row[bid + 512] = s3; wv_row[bid + 768] = s4;
        }
        if (bid == 0) {
            float v = 0.f, d2 = 0.f;
            for (int m = tid; m < 1024; m += 256) v += bv[m];
            dreduce(v, d2, shm + 1024);
            if (tid == 0) *bvsum = v;
        }
    } else {
        int n0i, b0i, ks;
        nt_map(bid - 256, n0i, b0i, ks);
        int n0 = n0i * 64, b0 = b0i * 8, k0 = ks * 128;
        load_A128(shm, mem, b0, k0);
        __syncthreads();
        nt_inner128v(shm, W0, k0, n0, P1a, ks, b0);
    }
}

// K2/K10: h = SiLU(LN(bias + sum8 P)) tile, then @W1 -> Pout. grid 512 (swizzled)
__global__ __launch_bounds__(256) void k_gemm_ln(const float* __restrict__ P, const float* __restrict__ bias,
                          const float* __restrict__ g, const float* __restrict__ be,
                          const float* __restrict__ W1, float* __restrict__ Pout) {
    __shared__ float shm[1040];
    int tid = threadIdx.x;
    int n0i, b0i, ks;
    nt_map(blockIdx.x, n0i, b0i, ks);
    int n0 = n0i * 64, b0 = b0i * 8, k0 = ks * 128;
    float* Atile = shm; float* stats = shm + 1024;
    int wv = tid >> 6, lane = tid & 63;
    const float4* b4 = (const float4*)bias;
    for (int rr = 0; rr < 2; ++rr) {
        int r = wv + rr * 4, b = b0 + r;
        float s = 0.f, sq = 0.f;
#pragma unroll
        for (int q = 0; q < 4; ++q) {
            int m4 = lane + 64 * q;
            float4 z4 = b4[m4];
#pragma unroll
            for (int k2 = 0; k2 < 8; ++k2) {
                float4 v = ((const float4*)(P + (size_t)k2 * 32768 + (size_t)b * 1024))[m4];
                z4 = f4add(z4, v);
            }
            int c0 = 4 * m4 - k0;
            if ((unsigned)c0 < 128u) *(float4*)(Atile + r * 128 + c0) = z4;
            s += z4.x + z4.y + z4.z + z4.w;
            sq += z4.x * z4.x + z4.y * z4.y + z4.z * z4.z + z4.w * z4.w;
        }
        wreduce(s, sq);
        if (lane == 0) {
            float mean = s * (1.f / 1024.f);
            stats[r] = mean;
            stats[8 + r] = rsqrtf(sq * (1.f / 1024.f) - mean * mean + LNEPS);
        }
    }
    __syncthreads();
    for (int i = tid; i < 1024; i += 256) {
        int r = i >> 7, c = i & 127, m = k0 + c;
        float xh = (Atile[i] - stats[r]) * stats[8 + r];
        float y = fmaf(xh, g[m], be[m]);
        float sg = 1.f / (1.f + __expf(-y));
        Atile[i] = y * sg;
    }
    __syncthreads();
    nt_inner128v(Atile, W1, k0, n0, Pout, ks, b0);
}

// K3: LN2 recompute + cb partial + mo@Wk^T slice. grid 1024 (swizzled T)
__global__ __launch_bounds__(256) void k_wpart(const float* __restrict__ P2a, const float* __restrict__ memb1,
                        const float* __restrict__ lng1, const float* __restrict__ lnb1,
                        const float* __restrict__ bk, const float* __restrict__ Wk,
                        float* __restrict__ wpart, float* __restrict__ cbpart) {
    __shared__ float shm[136];
    int tid = threadIdx.x;
    int dc, b, mc;
    t_map(blockIdx.x, dc, b, mc);
    int m0 = mc * 128;
    float* red = shm + 128;
    float4 z4 = ((const float4*)memb1)[tid];
#pragma unroll
    for (int k2 = 0; k2 < 8; ++k2) {
        float4 v = ((const float4*)(P2a + (size_t)k2 * 32768 + (size_t)b * 1024))[tid];
        z4 = f4add(z4, v);
    }
    float s = z4.x + z4.y + z4.z + z4.w;
    float sq = z4.x * z4.x + z4.y * z4.y + z4.z * z4.z + z4.w * z4.w;
    int c0 = 4 * tid - m0;
    if ((unsigned)c0 < 128u) *(float4*)(shm + c0) = z4;
    dreduce(s, sq, red);
    float mean = s * (1.f / 1024.f);
    float rstd = rsqrtf(sq * (1.f / 1024.f) - mean * mean + LNEPS);
    if (tid < 128) {
        int m = m0 + tid;
        float xh = (shm[tid] - mean) * rstd;
        float y = fmaf(xh, lng1[m], lnb1[m]);
        float sg = 1.f / (1.f + __expf(-y));
        shm[tid] = y * sg;
    }
    __syncthreads();
    if (dc == 0) {
        float c = (tid < 128) ? bk[m0 + tid] * shm[tid] : 0.f;
        float d2 = 0.f;
        dreduce(c, d2, red);
        if (tid == 0) cbpart[mc * 32 + b] = c;
    }
    t_inner(shm, Wk, dc * 256, m0, wpart + (size_t)(mc * 32 + b) * 1024 + dc * 256);
}

// K4: one pass over X (NT loads) + 1024 rider blocks doing mem@{Wf_bot,Wu_bot}.
// grid 2048, 1D. No cross-block sync anywhere.
__global__ __launch_bounds__(256) void k_bigpass(const float* __restrict__ X, const float* __restrict__ wpart,
                          const float* __restrict__ wv_row, const float* __restrict__ cbpart,
                          const float* __restrict__ bvsum, const float* __restrict__ mem,
                          const float* __restrict__ Wfb, const float* __restrict__ Wub,
                          float* __restrict__ t_part, float* __restrict__ p_part,
                          float* __restrict__ rs_part,
                          float* __restrict__ Pfm, float* __restrict__ Pum) {
    __shared__ float red[4][1024];
    __shared__ float rsum_s[4];
    int bid = blockIdx.x;
    if (bid >= 1024) {   // riders: X-independent gate GEMMs
        int t = bid - 1024, z = t >> 9;
        int n0i, b0i, ks;
        nt_map(t & 511, n0i, b0i, ks);
        int n0 = n0i * 64, b0 = b0i * 8, k0 = ks * 128;
        float* Atile = &red[0][0];
        load_A128(Atile, mem, b0, k0);
        __syncthreads();
        if (z == 0) nt_inner128v(Atile, Wfb, k0, n0, Pfm, ks, b0);
        else        nt_inner128v(Atile, Wub, k0, n0, Pum, ks, b0);
        return;
    }
    int b = bid >> 5, ch = bid & 31;
    int wv = threadIdx.x >> 6, lane = threadIdx.x & 63;
    float4 wreg[4], tacc[4], pacc[4];
    const float4* wp4 = (const float4*)wpart;
    const float4* wr4 = (const float4*)wv_row;
#pragma unroll
    for (int j = 0; j < 4; ++j) {
        int d4 = lane + 64 * j;
        float4 a = make_float4(0.f, 0.f, 0.f, 0.f);
#pragma unroll
        for (int mc = 0; mc < 8; ++mc) a = f4add(a, wp4[(size_t)(mc * 32 + b) * 256 + d4]);
        float4 wr = wr4[d4];
        wreg[j].x = 1024.f * a.x - wr.x;
        wreg[j].y = 1024.f * a.y - wr.y;
        wreg[j].z = 1024.f * a.z - wr.z;
        wreg[j].w = 1024.f * a.w - wr.w;
        tacc[j] = make_float4(0.f, 0.f, 0.f, 0.f);
        pacc[j] = make_float4(0.f, 0.f, 0.f, 0.f);
    }
    float cbs = 0.f;
#pragma unroll
    for (int mc = 0; mc < 8; ++mc) cbs += cbpart[mc * 32 + b];
    float cbv = 1024.f * cbs - *bvsum;
    float rloc = 0.f;
    int s0r = ch * 64 + wv * 16;
#pragma unroll 2
    for (int i = 0; i < 16; ++i) {
        const f32x4* xr = (const f32x4*)(X + ((size_t)b * Sc + s0r + i) * Dc);
        f32x4 x[4]; float pp = 0.f;
#pragma unroll
        for (int j = 0; j < 4; ++j) {
            x[j] = __builtin_nontemporal_load(xr + lane + 64 * j);
            pp += x[j].x * wreg[j].x + x[j].y * wreg[j].y + x[j].z * wreg[j].z + x[j].w * wreg[j].w;
        }
#pragma unroll
        for (int o = 32; o; o >>= 1) pp += __shfl_xor(pp, o);
        float r = pp + cbv;
        rloc += r;
#pragma unroll
        for (int j = 0; j < 4; ++j) {
            tacc[j].x = fmaf(x[j].x, r, tacc[j].x);
            tacc[j].y = fmaf(x[j].y, r, tacc[j].y);
            tacc[j].z = fmaf(x[j].z, r, tacc[j].z);
            tacc[j].w = fmaf(x[j].w, r, tacc[j].w);
            pacc[j].x += x[j].x; pacc[j].y += x[j].y;
            pacc[j].z += x[j].z; pacc[j].w += x[j].w;
        }
    }
    float4* redv = (float4*)red[wv];
#pragma unroll
    for (int j = 0; j < 4; ++j) redv[lane + 64 * j] = tacc[j];
    if (lane == 0) rsum_s[wv] = rloc;
    __syncthreads();
    size_t pb = ((size_t)b * 32 + ch) * 1024;
    for (int j = 0; j < 4; ++j) {
        int d = threadIdx.x + 256 * j;
        t_part[pb + d] = red[0][d] + red[1][d] + red[2][d] + red[3][d];
    }
    if (threadIdx.x == 0) rs_part[b * 32 + ch] = rsum_s[0] + rsum_s[1] + rsum_s[2] + rsum_s[3];
    __syncthreads();
#pragma unroll
    for (int j = 0; j < 4; ++j) redv[lane + 64 * j] = pacc[j];
    __syncthreads();
    for (int j = 0; j < 4; ++j) {
        int d = threadIdx.x + 256 * j;
        p_part[pb + d] = red[0][d] + red[1][d] + red[2][d] + red[3][d];
    }
}

// K5: chunk reduce -> tbuf, pooled(scaled), rsv. grid 32
__global__ __launch_bounds__(256) void k_reduce(const float* __restrict__ t_part, const float* __restrict__ p_part,
                         const float* __restrict__ rs_part,
                         float* __restrict__ tbuf, float* __restrict__ pooled,
                         float* __restrict__ rsv) {
    int idx = blockIdx.x * 256 + threadIdx.x;      // [0, 8192) float4 slots
    int b = idx >> 8, d4 = idx & 255;
    const float4* tp = (const float4*)t_part + (size_t)b * 8192 + d4;
    const float4* pp = (const float4*)p_part + (size_t)b * 8192 + d4;
    float4 st = make_float4(0.f, 0.f, 0.f, 0.f);
    float4 sp = make_float4(0.f, 0.f, 0.f, 0.f);
#pragma unroll 8
    for (int ch = 0; ch < 32; ++ch) {
        st = f4add(st, tp[(size_t)ch * 256]);
        sp = f4add(sp, pp[(size_t)ch * 256]);
    }
    ((float4*)tbuf)[idx] = st;
    sp.x *= (1.f / 2048.f); sp.y *= (1.f / 2048.f);
    sp.z *= (1.f / 2048.f); sp.w *= (1.f / 2048.f);
    ((float4*)pooled)[idx] = sp;
    if (blockIdx.x == 0 && threadIdx.x < 32) {
        float s = 0.f;
        for (int ch = 0; ch < 32; ++ch) s += rs_part[threadIdx.x * 32 + ch];
        rsv[threadIdx.x] = s;
    }
}

// K6: 3 GEMMs in one launch (mem-half gates moved to bigpass riders). grid 1536
__global__ __launch_bounds__(256) void k_gates(const float* __restrict__ tbuf, const float* __restrict__ pooled,
                        const float* __restrict__ Wk, const float* __restrict__ Wf,
                        const float* __restrict__ Wu,
                        float* __restrict__ Pg, float* __restrict__ Pfp, float* __restrict__ Pup) {
    __shared__ float Atile[1024];
    int bid = blockIdx.x;
    int z = bid >> 9;
    int n0i, b0i, ks;
    nt_map(bid & 511, n0i, b0i, ks);
    int n0 = n0i * 64, b0 = b0i * 8, k0 = ks * 128;
    const float* A; const float* W; float* P;
    if (z == 0)      { A = tbuf;   W = Wk; P = Pg; }
    else if (z == 1) { A = pooled; W = Wf; P = Pfp; }
    else             { A = pooled; W = Wu; P = Pup; }
    load_A128(Atile, A, b0, k0);
    __syncthreads();
    nt_inner128v(Atile, W, k0, n0, P, ks, b0);
}

// K7/K8: LN-bwd recompute + gemm-T slice. grid 1024 (swizzled T; rsv direct)
__global__ __launch_bounds__(256) void k_lnbwd_gemmT(const float* __restrict__ Pz, const float* __restrict__ bias,
                              const float* __restrict__ g, const float* __restrict__ be,
                              const float* __restrict__ Pgrad, int mode,
                              const float* __restrict__ bk, const float* __restrict__ rsv,
                              const float* __restrict__ W, float* __restrict__ Pout) {
    __shared__ float shm[392];
    int tid = threadIdx.x;
    int dc, b, mc;
    t_map(blockIdx.x, dc, b, mc);
    int m0 = mc * 128;
    float* red = shm + 384;
    float rsb = mode ? rsv[b] : 0.f;
    float4 z4 = ((const float4*)bias)[tid];
#pragma unroll
    for (int k2 = 0; k2 < 8; ++k2) {
        float4 v = ((const float4*)(Pz + (size_t)k2 * 32768 + (size_t)b * 1024))[tid];
        z4 = f4add(z4, v);
    }
    float s = z4.x + z4.y + z4.z + z4.w;
    float sq = z4.x * z4.x + z4.y * z4.y + z4.z * z4.z + z4.w * z4.w;
    dreduce(s, sq, red);
    float mean = s * (1.f / 1024.f);
    float rstd = rsqrtf(sq * (1.f / 1024.f) - mean * mean + LNEPS);
    float4 g4 = make_float4(0.f, 0.f, 0.f, 0.f);
#pragma unroll
    for (int k2 = 0; k2 < 8; ++k2) {
        float4 v = ((const float4*)(Pgrad + (size_t)k2 * 32768 + (size_t)b * 1024))[tid];
        g4 = f4add(g4, v);
    }
    if (mode) {
        float4 bk4 = ((const float4*)bk)[tid];
        g4.x = SCv * (g4.x + bk4.x * rsb);
        g4.y = SCv * (g4.y + bk4.y * rsb);
        g4.z = SCv * (g4.z + bk4.z * rsb);
        g4.w = SCv * (g4.w + bk4.w * rsb);
    }
    float4 gg = ((const float4*)g)[tid], bb = ((const float4*)be)[tid];
    float sa = 0.f, sax = 0.f;
    float4 a4, xh4;
    {
        xh4.x = (z4.x - mean) * rstd;
        float y = fmaf(xh4.x, gg.x, bb.x);
        float sg2 = 1.f / (1.f + __expf(-y));
        a4.x = g4.x * (sg2 * (1.f + y * (1.f - sg2))) * gg.x;
        sa += a4.x; sax += a4.x * xh4.x;
        xh4.y = (z4.y - mean) * rstd;
        y = fmaf(xh4.y, gg.y, bb.y);
        sg2 = 1.f / (1.f + __expf(-y));
        a4.y = g4.y * (sg2 * (1.f + y * (1.f - sg2))) * gg.y;
        sa += a4.y; sax += a4.y * xh4.y;
        xh4.z = (z4.z - mean) * rstd;
        y = fmaf(xh4.z, gg.z, bb.z);
        sg2 = 1.f / (1.f + __expf(-y));
        a4.z = g4.z * (sg2 * (1.f + y * (1.f - sg2))) * gg.z;
        sa += a4.z; sax += a4.z * xh4.z;
        xh4.w = (z4.w - mean) * rstd;
        y = fmaf(xh4.w, gg.w, bb.w);
        sg2 = 1.f / (1.f + __expf(-y));
        a4.w = g4.w * (sg2 * (1.f + y * (1.f - sg2))) * gg.w;
        sa += a4.w; sax += a4.w * xh4.w;
    }
    int c0 = 4 * tid - m0;
    if ((unsigned)c0 < 128u) {
        *(float4*)(shm + c0) = a4;
        *(float4*)(shm + 128 + c0) = xh4;
    }
    dreduce(sa, sax, red);
    float ma = sa * (1.f / 1024.f), mx = sax * (1.f / 1024.f);
    if (tid < 128) shm[256 + tid] = rstd * (shm[tid] - ma - shm[128 + tid] * mx);
    __syncthreads();
    t_inner(shm + 256, W, dc * 256, m0, Pout + (size_t)(mc * 32 + b) * 1024 + dc * 256);
}

// K9: gate/update recompute -> nmem tile -> @W0 partials; writes out_nm. grid 512 (swizzled)
__global__ __launch_bounds__(256) void k_upd_g3(const float* __restrict__ Pfm, const float* __restrict__ Pfp,
                         const float* __restrict__ Pum, const float* __restrict__ Pup,
                         const float* __restrict__ surp,
                         const float* __restrict__ bf, const float* __restrict__ bu,
                         const float* __restrict__ mem, const float* __restrict__ mom,
                         const float* __restrict__ eta, const float* __restrict__ theta,
                         const float* __restrict__ W0, float* __restrict__ P3a,
                         float* __restrict__ out_nm) {
    __shared__ float Atile[1024];
    int tid = threadIdx.x;
    int n0i, b0i, ks;
    nt_map(blockIdx.x, n0i, b0i, ks);
    int n0 = n0i * 64, b0 = b0i * 8, k0 = ks * 128;
    float etav = eta[0], thv = theta[0];
    int r = tid >> 5, c4 = tid & 31, b = b0 + r;
    int m4 = (k0 >> 2) + c4;
    float4 zf = ((const float4*)bf)[m4];
    float4 zu = ((const float4*)bu)[m4];
    float4 sv = make_float4(0.f, 0.f, 0.f, 0.f);
#pragma unroll
    for (int k2 = 0; k2 < 8; ++k2) {
        size_t ob4 = (size_t)k2 * 8192 + (size_t)b * 256 + m4;
        zf = f4add(zf, f4add(((const float4*)Pfm)[ob4], ((const float4*)Pfp)[ob4]));
        zu = f4add(zu, f4add(((const float4*)Pum)[ob4], ((const float4*)Pup)[ob4]));
        sv = f4add(sv, ((const float4*)surp)[ob4]);
    }
    float4 me = ((const float4*)mem)[(size_t)b * 256 + m4];
    float4 mo = ((const float4*)mom)[(size_t)b * 256 + m4];
    float4 nm;
    {
        float f = 1.f / (1.f + __expf(-zf.x)), u = 1.f / (1.f + __expf(-zu.x));
        nm.x = (1.f - f) * me.x + u * (etav * mo.x + thv * sv.x);
        f = 1.f / (1.f + __expf(-zf.y)); u = 1.f / (1.f + __expf(-zu.y));
        nm.y = (1.f - f) * me.y + u * (etav * mo.y + thv * sv.y);
        f = 1.f / (1.f + __expf(-zf.z)); u = 1.f / (1.f + __expf(-zu.z));
        nm.z = (1.f - f) * me.z + u * (etav * mo.z + thv * sv.z);
        f = 1.f / (1.f + __expf(-zf.w)); u = 1.f / (1.f + __expf(-zu.w));
        nm.w = (1.f - f) * me.w + u * (etav * mo.w + thv * sv.w);
    }
    *(float4*)(Atile + r * 128 + 4 * c4) = nm;
    if (n0i == 0) ((float4*)out_nm)[(size_t)b * 256 + m4] = nm;
    __syncthreads();
    nt_inner128v(Atile, W0, k0, n0, P3a, ks, b0);
}

// K11: final LN -> out. grid 32
__global__ __launch_bounds__(256) void k_final(const float* __restrict__ P4a, const float* __restrict__ memb1,
                        const float* __restrict__ lng1, const float* __restrict__ lnb1,
                        float* __restrict__ out) {
    __shared__ float sm[8];
    int b = blockIdx.x, tid = threadIdx.x;
    float4 z4 = ((const float4*)memb1)[tid];
#pragma unroll
    for (int k2 = 0; k2 < 8; ++k2) {
        float4 v = ((const float4*)(P4a + (size_t)k2 * 32768 + (size_t)b * 1024))[tid];
        z4 = f4add(z4, v);
    }
    float s = z4.x + z4.y + z4.z + z4.w;
    float sq = z4.x * z4.x + z4.y * z4.y + z4.z * z4.z + z4.w * z4.w;
    dreduce(s, sq, sm);
    float mean = s * (1.f / 1024.f);
    float rstd = rsqrtf(sq * (1.f / 1024.f) - mean * mean + LNEPS);
    float4 gg = ((const float4*)lng1)[tid], bb = ((const float4*)lnb1)[tid];
    float4 o;
    {
        float xh = (z4.x - mean) * rstd, y = fmaf(xh, gg.x, bb.x);
        o.x = y / (1.f + __expf(-y));
        xh = (z4.y - mean) * rstd; y = fmaf(xh, gg.y, bb.y);
        o.y = y / (1.f + __expf(-y));
        xh = (z4.z - mean) * rstd; y = fmaf(xh, gg.z, bb.z);
        o.z = y / (1.f + __expf(-y));
        xh = (z4.w - mean) * rstd; y = fmaf(xh, gg.w, bb.w);
        o.w = y / (1.f + __expf(-y));
    }
    ((float4*)out)[(size_t)b * 256 + tid] = o;
}

extern "C" void kernel_launch(void* const* d_in, const int* in_sizes, int n_in,
                              void* d_out, int out_size, void* d_ws, size_t ws_size,
                              hipStream_t stream) {
    const float* X    = (const float*)d_in[0];
    const float* mem  = (const float*)d_in[1];
    const float* mom  = (const float*)d_in[2];
    const float* Wk   = (const float*)d_in[3];
    const float* bk   = (const float*)d_in[4];
    const float* Wv   = (const float*)d_in[5];
    const float* bv   = (const float*)d_in[6];
    const float* memW = (const float*)d_in[7];
    const float* memb = (const float*)d_in[8];
    const float* lng  = (const float*)d_in[9];
    const float* lnb  = (const float*)d_in[10];
    const float* Wf   = (const float*)d_in[11];
    const float* bf   = (const float*)d_in[12];
    const float* Wu   = (const float*)d_in[15];
    const float* bu   = (const float*)d_in[16];
    const float* eta  = (const float*)d_in[17];
    const float* theta= (const float*)d_in[18];
    float* out = (float*)d_out;

    const size_t BM = (size_t)Bc * Mc;     // 32768
    float* ws = (float*)d_ws;
    float* P1a    = ws;                    // 8*BM each
    float* P2a    = ws + 8 * BM;
    float* wpart  = ws + 16 * BM;
    float* Pg     = ws + 24 * BM;
    float* Pfp    = ws + 32 * BM;
    float* Pup    = ws + 40 * BM;
    float* Pfm    = ws + 48 * BM;
    float* Pum    = ws + 56 * BM;
    float* ghp    = ws + 64 * BM;
    float* surp   = ws + 72 * BM;
    float* P3a    = ws + 80 * BM;
    float* P4a    = ws + 88 * BM;
    float* t_part = ws + 96 * BM;          // 32*BM
    float* p_part = ws + 128 * BM;         // 32*BM
    float* tbuf   = ws + 160 * BM;         // BM
    float* pooled = ws + 161 * BM;         // BM
    float* wv_row = ws + 162 * BM;         // 1024
    float* bvsum  = wv_row + 1024;         // 1
    float* cbpart = bvsum + 1;             // 256
    float* rs_part= cbpart + 256;          // 1024
    float* rsv    = rs_part + 1024;        // 32

    const float* W0 = memW;
    const float* W1 = memW + (size_t)Mc * Mc;
    const float* Wfb = Wf + (size_t)1024 * 1024;
    const float* Wub = Wu + (size_t)1024 * 1024;

    k_front<<<768, 256, 0, stream>>>(Wv, bv, mem, W0, wv_row, bvsum, P1a);
    k_gemm_ln<<<512, 256, 0, stream>>>(P1a, memb, lng, lnb, W1, P2a);
    k_wpart<<<1024, 256, 0, stream>>>(P2a, memb + 1024, lng + 1024, lnb + 1024, bk, Wk, wpart, cbpart);
    k_bigpass<<<2048, 256, 0, stream>>>(X, wpart, wv_row, cbpart, bvsum, mem, Wfb, Wub,
                                        t_part, p_part, rs_part, Pfm, Pum);
    k_reduce<<<32, 256, 0, stream>>>(t_part, p_part, rs_part, tbuf, pooled, rsv);
    k_gates<<<1536, 256, 0, stream>>>(tbuf, pooled, Wk, Wf, Wu, Pg, Pfp, Pup);
    k_lnbwd_gemmT<<<1024, 256, 0, stream>>>(P2a, memb + 1024, lng + 1024, lnb + 1024, Pg, 1, bk, rsv, W1, ghp);
    k_lnbwd_gemmT<<<1024, 256, 0, stream>>>(P1a, memb, lng, lnb, ghp, 0, bk, rsv, W0, surp);
    k_upd_g3<<<512, 256, 0, stream>>>(Pfm, Pfp, Pum, Pup, surp, bf, bu, mem, mom, eta, theta, W0, P3a, out + BM);
    k_gemm_ln<<<512, 256, 0, stream>>>(P3a, memb, lng, lnb, W1, P4a);
    k_final<<<32, 256, 0, stream>>>(P4a, memb + 1024, lng + 1024, lnb + 1024, out);
}